// Round 1
// baseline (341.639 us; speedup 1.0000x reference)
//
#include <hip/hip_runtime.h>
#include <cstdint>
#include <cstddef>

// ============================================================================
// MaskGenerator R5: k_faug FFT rebuilt as stage-PAIRED radix-2 (two stages per
// LDS round trip, float2-packed complex, e+(e>>3) swizzle + odd row pitch).
// Butterfly math is expression-identical to the validated radix-2 chain, so
// results are bit-exact vs R4. Syncs 19->12, LDS ops ~2.5x down.
// k_init z-draw fused into k_mlp1 (same threefry counters); k_init shrunk to
// wp/sh only. k_gemm/MLP chain unchanged (validated). PRNG unchanged.
// ============================================================================

typedef unsigned int u32;
typedef unsigned short u16;

#define Bd 256
#define Ld 512
#define Fd 64
#define Nd 32768            // Ld*Fd

struct U2 { u32 a, b; };

__device__ __forceinline__ u32 rotl32(u32 x, int r){ return (x << r) | (x >> (32 - r)); }

__device__ __forceinline__ U2 tf2x32(u32 k0, u32 k1, u32 x0, u32 x1){
  u32 ks2 = k0 ^ k1 ^ 0x1BD11BDAu;
  x0 += k0; x1 += k1;
#define TFR4(r0,r1,r2,r3) \
  x0 += x1; x1 = rotl32(x1, r0); x1 ^= x0; \
  x0 += x1; x1 = rotl32(x1, r1); x1 ^= x0; \
  x0 += x1; x1 = rotl32(x1, r2); x1 ^= x0; \
  x0 += x1; x1 = rotl32(x1, r3); x1 ^= x0;
  TFR4(13,15,26,6)  x0 += k1;  x1 += ks2 + 1u;
  TFR4(17,29,16,24) x0 += ks2; x1 += k0 + 2u;
  TFR4(13,15,26,6)  x0 += k0;  x1 += k1 + 3u;
  TFR4(17,29,16,24) x0 += k1;  x1 += ks2 + 4u;
  TFR4(13,15,26,6)  x0 += ks2; x1 += k0 + 5u;
#undef TFR4
  U2 r; r.a = x0; r.b = x1; return r;
}

__device__ __forceinline__ u32 rb32(u32 k0, u32 k1, u32 i){
  U2 r = tf2x32(k0, k1, 0u, i);
  return r.a ^ r.b;
}

__device__ __forceinline__ U2 split_key(u32 k0, u32 k1, u32 j){
  return tf2x32(k0, k1, 0u, j);
}

__device__ __forceinline__ float sigmoidf_(float x){ return 1.0f / (1.0f + expf(-x)); }
__device__ __forceinline__ float softplusf_(float x){ return fmaxf(x, 0.0f) + log1pf(expf(-fabsf(x))); }
__device__ __forceinline__ float leakyf_(float x){ return (x > 0.0f) ? x : 0.2f * x; }

__device__ __forceinline__ float erfinvf_(float x){
  float w = -log1pf(-x * x);
  float p;
  if (w < 5.0f){
    w -= 2.5f;
    p =               2.81022636e-08f;
    p = fmaf(p, w,    3.43273939e-07f);
    p = fmaf(p, w,   -3.5233877e-06f);
    p = fmaf(p, w,   -4.39150654e-06f);
    p = fmaf(p, w,    0.00021858087f);
    p = fmaf(p, w,   -0.00125372503f);
    p = fmaf(p, w,   -0.00417768164f);
    p = fmaf(p, w,    0.246640727f);
    p = fmaf(p, w,    1.50140941f);
  } else {
    w = sqrtf(w) - 3.0f;
    p =              -0.000200214257f;
    p = fmaf(p, w,    0.000100950558f);
    p = fmaf(p, w,    0.00134934322f);
    p = fmaf(p, w,   -0.00367342844f);
    p = fmaf(p, w,    0.00573950773f);
    p = fmaf(p, w,   -0.0076224613f);
    p = fmaf(p, w,    0.00943887047f);
    p = fmaf(p, w,    1.00167406f);
    p = fmaf(p, w,    2.83297682f);
  }
  return p * x;
}

__device__ __forceinline__ float uniform_from_bits(u32 bits){
  return __uint_as_float((bits >> 9) | 0x3f800000u) - 1.0f;
}

__device__ __forceinline__ float normal_from_bits(u32 bits){
  float u01 = uniform_from_bits(bits);
  const float lo = -0.99999994f;
  float v = fmaf(u01, 2.0f, lo);
  v = fmaxf(lo, v);
  return 1.41421356f * erfinvf_(v);
}

__device__ __forceinline__ int warp_idx_(int t, int wp, int sh){
  int tps = t + sh;
  int pos = (t >= wp) ? ((tps < Ld - 1) ? tps : (Ld - 1)) : t;
  int neg = ((t >= wp + sh) && (t < Ld + sh)) ? (t - sh) : t;
  return (sh > 0) ? pos : ((sh < 0) ? neg : t);
}

__device__ __forceinline__ u32 pack_bf16_2(float a, float b){
  u32 ua = __float_as_uint(a), ub = __float_as_uint(b);
  u32 ra = (ua + 0x7FFFu + ((ua >> 16) & 1u)) >> 16;
  u32 rb = (ub + 0x7FFFu + ((ub >> 16) & 1u)) >> 16;
  return (ra & 0xFFFFu) | (rb << 16);
}
__device__ __forceinline__ u16 f2bf(float a){
  u32 ua = __float_as_uint(a);
  return (u16)((ua + 0x7FFFu + ((ua >> 16) & 1u)) >> 16);
}
__device__ __forceinline__ float bf2f(u16 v){
  return __uint_as_float(((u32)v) << 16);
}

__device__ __forceinline__ int swz_(int v){
  return ((v >> 2) & 7) ^ ((v & 3) << 1);
}
__device__ __forceinline__ int rev9_(int k){
  return (int)(__brev((u32)k) >> 23);
}

// ---------------------------------------------------------------------------
// K0: wp/sh randint draws only (z-draw fused into k_mlp1). grid(1) x 256.
// ---------------------------------------------------------------------------
__global__ __launch_bounds__(256) void k_init(int* __restrict__ wp, int* __restrict__ shv,
                                              const float* __restrict__ p_shift){
  int b = threadIdx.x;
  float s_shift = sigmoidf_(p_shift[0]);
  int wsteps = (int)(51.2f * s_shift);
  U2 kwp = split_key(0u, 42u, 2u);
  U2 ksh = split_key(0u, 42u, 3u);
  {
    U2 k1 = split_key(kwp.a, kwp.b, 0u);
    U2 k2 = split_key(kwp.a, kwp.b, 1u);
    u32 hi = rb32(k1.a, k1.b, (u32)b);
    u32 lo = rb32(k2.a, k2.b, (u32)b);
    u32 span = (u32)(Ld - 2 * wsteps);
    u32 mult = 65536u % span; mult = (mult * mult) % span;
    u32 off = ((hi % span) * mult + (lo % span)) % span;
    wp[b] = wsteps + (int)off;
  }
  {
    U2 k1 = split_key(ksh.a, ksh.b, 0u);
    U2 k2 = split_key(ksh.a, ksh.b, 1u);
    u32 hi = rb32(k1.a, k1.b, (u32)b);
    u32 lo = rb32(k2.a, k2.b, (u32)b);
    u32 span = (u32)(2 * wsteps + 1);
    u32 mult = 65536u % span; mult = (mult * mult) % span;
    u32 off = ((hi % span) * mult + (lo % span)) % span;
    shv[b] = -wsteps + (int)off;
  }
}

// ---------------------------------------------------------------------------
// MLP chain. k_mlp1 now draws its z-row in LDS (same threefry counters as the
// old k_init: counter = b*64 + k). k_mlp2/3, k_scale unchanged (validated).
// ---------------------------------------------------------------------------
__global__ __launch_bounds__(128) void k_mlp1(const float* __restrict__ w1,
                                              const float* __restrict__ b1, float* __restrict__ h1){
  __shared__ float zs[64];
  int b = blockIdx.x, n = threadIdx.x;
  if (n < 64){
    U2 kz = split_key(0u, 42u, 0u);
    zs[n] = normal_from_bits(rb32(kz.a, kz.b, (u32)(b * 64 + n)));
  }
  __syncthreads();
  float acc = b1[n];
  #pragma unroll 8
  for (int k = 0; k < 64; ++k) acc = fmaf(zs[k], w1[k * 128 + n], acc);
  h1[b * 128 + n] = leakyf_(acc);
}

__global__ __launch_bounds__(256) void k_mlp2(const float* __restrict__ h1, const float* __restrict__ w2,
                                              const float* __restrict__ b2, float* __restrict__ h2){
  int b = blockIdx.x, n = threadIdx.x;
  const float* hr = h1 + b * 128;
  float acc = b2[n];
  #pragma unroll 8
  for (int k = 0; k < 128; ++k) acc = fmaf(hr[k], w2[k * 256 + n], acc);
  h2[b * 256 + n] = leakyf_(acc);
}

__global__ __launch_bounds__(256) void k_mlp3(const float* __restrict__ h2, const float* __restrict__ w3,
                                              const float* __restrict__ b3, u16* __restrict__ h3b){
  int b = blockIdx.x, n = threadIdx.x;
  const float* hr = h2 + b * 256;
  float acc = b3[n];
  #pragma unroll 8
  for (int k = 0; k < 256; ++k) acc = fmaf(hr[k], w3[k * 256 + n], acc);
  h3b[b * 256 + n] = f2bf(leakyf_(acc));
}

__global__ __launch_bounds__(256) void k_scale(const u16* __restrict__ h3b, const float* __restrict__ wsc,
                                               const float* __restrict__ bsc, const float* __restrict__ p_scale,
                                               float* __restrict__ scl){
  int tid = threadIdx.x;
  int b = blockIdx.x * 4 + (tid >> 6);
  int f = tid & 63;
  float acc = bsc[f];
  for (int k = 0; k < 256; ++k) acc = fmaf(bf2f(h3b[b * 256 + k]), wsc[k * 64 + f], acc);
  float s_scale = sigmoidf_(p_scale[0]);
  scl[b * 64 + f] = 1.0f + (softplusf_(acc) - 0.5f) * 0.2f * s_scale;
}

// ---------------------------------------------------------------------------
// k_gemm: unchanged from R3/R4 (validated)
// ---------------------------------------------------------------------------
typedef short short8 __attribute__((ext_vector_type(8)));
typedef float f32x4 __attribute__((ext_vector_type(4)));
union Frag { uint4 u; short8 s; };

__global__ __launch_bounds__(256, 2) void k_gemm(
    const u16* __restrict__ h3b,
    const float* __restrict__ wm, const float* __restrict__ bm,
    const float* __restrict__ wn, const float* __restrict__ bn,
    u16* __restrict__ logM, u16* __restrict__ logN)
{
  __shared__ __align__(16) u32 As [128 * 32];
  __shared__ __align__(16) u32 Bs0[128 * 32];
  __shared__ __align__(16) u32 Bs1[128 * 32];

  const int tid  = threadIdx.x;
  const int lane = tid & 63;
  const int w    = tid >> 6;
  const int q    = lane >> 4;
  const int lo   = lane & 15;
  const int nt0  = blockIdx.x << 7;
  const int b0   = blockIdx.y << 7;
  const int wr   = (w >> 1) << 6;
  const int wc   = (w & 1) << 6;

  const int p  = lane >> 3;
  const int c8 = lane & 7;
  const int nb = (w << 5) + (p << 2);

  f32x4 accm[4][4], accn[4][4];
  #pragma unroll
  for (int i = 0; i < 4; ++i)
    #pragma unroll
    for (int j = 0; j < 4; ++j){ accm[i][j] = (f32x4)0.0f; accn[i][j] = (f32x4)0.0f; }

  for (int kc = 0; kc < 256; kc += 64){
    if (kc) __syncthreads();
    #pragma unroll
    for (int j = 0; j < 4; ++j){
      int idx  = j * 256 + tid;
      int row  = idx >> 3;
      int slot = idx & 7;
      int g    = slot ^ swz_(row);
      uint4 v  = *(const uint4*)(h3b + (size_t)(b0 + row) * 256 + kc + g * 8);
      *(uint4*)&As[row * 32 + slot * 4] = v;
    }
    #pragma unroll
    for (int cp = 0; cp < 4; ++cp){
      int c = cp * 8 + c8;
      size_t gb = (size_t)(kc + 2 * c) * Nd + nt0 + nb;
      float4 m0 = *(const float4*)(wm + gb);
      float4 m1 = *(const float4*)(wm + gb + Nd);
      float4 v0 = *(const float4*)(wn + gb);
      float4 v1 = *(const float4*)(wn + gb + Nd);
      int g = c >> 2, cl = c & 3;
      #pragma unroll
      for (int s = 0; s < 4; ++s){
        int n = nb + s;
        int addr = n * 32 + (g ^ swz_(n)) * 4 + cl;
        float a0 = (s == 0) ? m0.x : (s == 1) ? m0.y : (s == 2) ? m0.z : m0.w;
        float a1 = (s == 0) ? m1.x : (s == 1) ? m1.y : (s == 2) ? m1.z : m1.w;
        float b0f = (s == 0) ? v0.x : (s == 1) ? v0.y : (s == 2) ? v0.z : v0.w;
        float b1f = (s == 0) ? v1.x : (s == 1) ? v1.y : (s == 2) ? v1.z : v1.w;
        Bs0[addr] = pack_bf16_2(a0, a1);
        Bs1[addr] = pack_bf16_2(b0f, b1f);
      }
    }
    __syncthreads();

    #pragma unroll
    for (int u = 0; u < 2; ++u){
      int G = u * 4 + q;
      Frag af[4], bfm[4], bfn[4];
      #pragma unroll
      for (int mt = 0; mt < 4; ++mt){
        int row = wr + mt * 16 + lo;
        af[mt].u = *(const uint4*)&As[row * 32 + (G ^ swz_(row)) * 4];
      }
      #pragma unroll
      for (int nt = 0; nt < 4; ++nt){
        int n = wc + nt * 16 + lo;
        int ad = n * 32 + (G ^ swz_(n)) * 4;
        bfm[nt].u = *(const uint4*)&Bs0[ad];
        bfn[nt].u = *(const uint4*)&Bs1[ad];
      }
      #pragma unroll
      for (int mt = 0; mt < 4; ++mt){
        #pragma unroll
        for (int nt = 0; nt < 4; ++nt){
          accm[mt][nt] = __builtin_amdgcn_mfma_f32_16x16x32_bf16(af[mt].s, bfm[nt].s, accm[mt][nt], 0, 0, 0);
          accn[mt][nt] = __builtin_amdgcn_mfma_f32_16x16x32_bf16(af[mt].s, bfn[nt].s, accn[mt][nt], 0, 0, 0);
        }
      }
    }
  }

  #pragma unroll
  for (int nt = 0; nt < 4; ++nt){
    int n = nt0 + wc + nt * 16 + lo;
    float bmv = bm[n];
    float bnv = bn[n];
    #pragma unroll
    for (int mt = 0; mt < 4; ++mt){
      #pragma unroll
      for (int r = 0; r < 4; ++r){
        int b = b0 + wr + mt * 16 + q * 4 + r;
        size_t o = (size_t)b * Nd + n;
        logM[o] = f2bf(accm[mt][nt][r] + bmv);
        logN[o] = f2bf(accn[mt][nt][r] + bnv);
      }
    }
  }
}

// ---------------------------------------------------------------------------
// k_faug: stage-paired radix-2 FFT (bit-exact vs sequential radix-2).
//  - complex packed as float2; swizzle phys(e) = e + (e>>3); row pitch 578
//    (odd float2 pitch -> rows land at distinct bank offsets: 1156%32 = 4).
//  - forward: paired passes s = (9,8),(7,6),(5,4),(3,2), then trivial s=1.
//    group {base, base+q, base+2q, base+3q}, q = 2^(s-2);
//    twiddles W1 = tw[t1], W1b = tw[t1+128], W2 = tw[2*t1], t1 = pos<<(9-s).
//    phys deltas are carry-free: phys(base+k*q) = phys(base) + k*(q + q/8)
//    for q>=8, and + k*q for q=2 (low bits never carry past bit 3).
//  - inverse: trivial s=1, then paired (2,3),(4,5),(6,7),(8,9), conj twiddles.
//  - masked Hermitian repack + epilogue identical to R4 (PRNG untouched).
// ---------------------------------------------------------------------------
#define PITCH2 578

__device__ __forceinline__ int fphys(int e){ return e + (e >> 3); }

__global__ __launch_bounds__(256, 4) void k_faug(
    const float* __restrict__ x,
    const u16* __restrict__ logM, const u16* __restrict__ logN,
    const float* __restrict__ scl,
    const int* __restrict__ wp, const int* __restrict__ shv,
    const float* __restrict__ p_mask, const float* __restrict__ p_noise,
    const float* __restrict__ p_shift,
    float* __restrict__ out)
{
  __shared__ float2 C[8 * PITCH2];
  __shared__ float2 tw[256];

  const int tid = threadIdx.x;
  const int b   = blockIdx.x >> 2;
  const int f0  = (blockIdx.x & 3) << 4;

  float s_mask  = sigmoidf_(p_mask[0]);
  float s_noise = sigmoidf_(p_noise[0]);
  float s_shift = sigmoidf_(p_shift[0]);
  float s_mix   = 1.0f - s_shift;
  float ratio   = fminf(s_mix * 0.1f, 0.5f);
  float wa = 1.0f - s_mix - s_shift;
  wa = fminf(fmaxf(wa, 0.1f), 0.8f);
  float wb = s_mix * 0.5f;
  float wc = s_shift * 0.5f;
  float tot = wa + wb + wc;
  wa /= tot; wb /= tot; wc /= tot;
  bool pass = (s_mix < 0.01f);

  U2 kf  = split_key(0u, 42u, 4u);
  U2 knk = split_key(0u, 42u, 1u);
  const int wpb = wp[b];
  const int shb = shv[b];

  {
    float ang = -6.283185307179586f * ((float)tid / 512.0f);
    tw[tid] = make_float2(cosf(ang), sinf(ang));
  }

  // ---- stage in + pack pairs ----
  const float* xb = x + (size_t)b * Nd;
  #pragma unroll
  for (int s = 0; s < 8; ++s){
    int qq = (s << 8) + tid;        // float4 id, 0..2047
    int t  = qq >> 2;
    int f4 = qq & 3;
    float4 v = *(const float4*)(xb + t * 64 + f0 + (f4 << 2));
    int j = f4 << 1;
    int pt = fphys(t);
    C[j * PITCH2 + pt]       = make_float2(v.x, v.y);
    C[(j + 1) * PITCH2 + pt] = make_float2(v.z, v.w);
  }
  __syncthreads();

  // ---- forward DIF, paired stages (9,8),(7,6),(5,4),(3,2) ----
  #pragma unroll
  for (int ps = 0; ps < 4; ++ps){
    const int s  = 9 - 2 * ps;            // 9,7,5,3
    const int q  = 1 << (s - 2);          // 128,32,8,2
    const int dq = (q >= 8) ? (q + (q >> 3)) : q;   // 144,36,9,2
    float2 A[4][4]; float2 TW[4][3]; int P0[4];
    #pragma unroll
    for (int it = 0; it < 4; ++it){
      int G   = it * 256 + tid;
      int j   = G >> 7;
      int gi  = G & 127;
      int pos = gi & (q - 1);
      int base = ((gi >> (s - 2)) << s) + pos;
      int t1  = pos << (9 - s);
      TW[it][0] = tw[t1];
      TW[it][1] = tw[t1 + 128];
      TW[it][2] = tw[t1 << 1];
      int p0 = j * PITCH2 + fphys(base);
      P0[it] = p0;
      A[it][0] = C[p0];
      A[it][1] = C[p0 + dq];
      A[it][2] = C[p0 + 2 * dq];
      A[it][3] = C[p0 + 3 * dq];
    }
    #pragma unroll
    for (int it = 0; it < 4; ++it){
      float2 W1 = TW[it][0], W1b = TW[it][1], W2 = TW[it][2];
      float2 a0 = A[it][0], a1 = A[it][1], a2 = A[it][2], a3 = A[it][3];
      // stage s: butterflies (a0,a2) w=W1 ; (a1,a3) w=W1b
      float A0r = a0.x + a2.x, A0i = a0.y + a2.y;
      float d0r = a0.x - a2.x, d0i = a0.y - a2.y;
      float B0r = d0r * W1.x - d0i * W1.y;
      float B0i = d0r * W1.y + d0i * W1.x;
      float A1r = a1.x + a3.x, A1i = a1.y + a3.y;
      float d1r = a1.x - a3.x, d1i = a1.y - a3.y;
      float B1r = d1r * W1b.x - d1i * W1b.y;
      float B1i = d1r * W1b.y + d1i * W1b.x;
      // stage s-1: (A0,A1) and (B0,B1), both w=W2
      float o0r = A0r + A1r, o0i = A0i + A1i;
      float e0r = A0r - A1r, e0i = A0i - A1i;
      float o1r = e0r * W2.x - e0i * W2.y;
      float o1i = e0r * W2.y + e0i * W2.x;
      float o2r = B0r + B1r, o2i = B0i + B1i;
      float e1r = B0r - B1r, e1i = B0i - B1i;
      float o3r = e1r * W2.x - e1i * W2.y;
      float o3i = e1r * W2.y + e1i * W2.x;
      int p0 = P0[it];
      C[p0]          = make_float2(o0r, o0i);
      C[p0 + dq]     = make_float2(o1r, o1i);
      C[p0 + 2 * dq] = make_float2(o2r, o2i);
      C[p0 + 3 * dq] = make_float2(o3r, o3i);
    }
    __syncthreads();
  }

  // ---- forward trivial stage s=1 (w = tw[0] = 1) ----
  #pragma unroll
  for (int it = 0; it < 8; ++it){
    int p0 = it * PITCH2 + fphys(2 * tid);   // phys(2t+1) = phys(2t)+1, carry-free
    float2 u = C[p0], v = C[p0 + 1];
    C[p0]     = make_float2(u.x + v.x, u.y + v.y);
    C[p0 + 1] = make_float2(u.x - v.x, u.y - v.y);
  }
  __syncthreads();

  // ---- masked Hermitian repack at natural frequency k (unchanged math) ----
  #pragma unroll
  for (int it = 0; it < 8; ++it){
    int j = it;
    int k = tid;
    int nItr = (k == 0) ? 2 : 1;
    for (int e = 0; e < nItr; ++e){
      int kk = (e == 0) ? k : 256;
      int nk = (512 - kk) & 511;
      int pk = rev9_(kk), pn = rev9_(nk);
      int ak = j * PITCH2 + fphys(pk);
      int an = j * PITCH2 + fphys(pn);
      float2 zk = C[ak];
      float2 zn = C[an];
      float X0r = 0.5f * (zk.x + zn.x), X0i = 0.5f * (zk.y - zn.y);
      float X1r = 0.5f * (zk.y + zn.y), X1i = 0.5f * (zn.x - zk.x);
      int fA = f0 + (j << 1);
      u32 ck = (u32)((b * Ld + kk) * Fd + fA);
      u32 cn = (u32)((b * Ld + nk) * Fd + fA);
      float k0a = (uniform_from_bits(rb32(kf.a, kf.b, ck))      > ratio) ? 1.0f : 0.0f;
      float k0b = (uniform_from_bits(rb32(kf.a, kf.b, cn))      > ratio) ? 1.0f : 0.0f;
      float k1a = (uniform_from_bits(rb32(kf.a, kf.b, ck + 1u)) > ratio) ? 1.0f : 0.0f;
      float k1b = (uniform_from_bits(rb32(kf.a, kf.b, cn + 1u)) > ratio) ? 1.0f : 0.0f;
      float m0 = 0.5f * (k0a + k0b);
      float m1 = 0.5f * (k1a + k1b);
      // U[k] = m0*X0 + i*m1*X1 ; U[nk] = m0*conj(X0) + i*m1*conj(X1)
      C[ak] = make_float2(m0 * X0r - m1 * X1i, m0 * X0i + m1 * X1r);
      C[an] = make_float2(m0 * X0r + m1 * X1i, m1 * X1r - m0 * X0i);
    }
  }
  __syncthreads();

  // ---- inverse DIT trivial stage s=1 (conj(tw[0]) = 1) ----
  #pragma unroll
  for (int it = 0; it < 8; ++it){
    int p0 = it * PITCH2 + fphys(2 * tid);
    float2 u = C[p0], v = C[p0 + 1];
    C[p0]     = make_float2(u.x + v.x, u.y + v.y);
    C[p0 + 1] = make_float2(u.x - v.x, u.y - v.y);
  }
  __syncthreads();

  // ---- inverse DIT, paired stages (2,3),(4,5),(6,7),(8,9) ----
  #pragma unroll
  for (int ps = 0; ps < 4; ++ps){
    const int s  = 3 + 2 * ps;            // 3,5,7,9
    const int q  = 1 << (s - 2);          // 2,8,32,128
    const int dq = (q >= 8) ? (q + (q >> 3)) : q;
    float2 A[4][4]; float2 TW[4][3]; int P0[4];
    #pragma unroll
    for (int it = 0; it < 4; ++it){
      int G   = it * 256 + tid;
      int j   = G >> 7;
      int gi  = G & 127;
      int pos = gi & (q - 1);
      int base = ((gi >> (s - 2)) << s) + pos;
      int t1  = pos << (9 - s);
      TW[it][0] = tw[t1];
      TW[it][1] = tw[t1 + 128];
      TW[it][2] = tw[t1 << 1];
      int p0 = j * PITCH2 + fphys(base);
      P0[it] = p0;
      A[it][0] = C[p0];
      A[it][1] = C[p0 + dq];
      A[it][2] = C[p0 + 2 * dq];
      A[it][3] = C[p0 + 3 * dq];
    }
    #pragma unroll
    for (int it = 0; it < 4; ++it){
      float2 W1 = TW[it][0], W1b = TW[it][1], W2 = TW[it][2];
      float2 x0 = A[it][0], x1 = A[it][1], x2 = A[it][2], x3 = A[it][3];
      // stage s-1: pairs (x0,x1) and (x2,x3), w = W2 (conj form: v*conj(w))
      float t1x = x1.x * W2.x + x1.y * W2.y;
      float t1y = x1.y * W2.x - x1.x * W2.y;
      float A0r = x0.x + t1x, A0i = x0.y + t1y;
      float A1r = x0.x - t1x, A1i = x0.y - t1y;
      float t3x = x3.x * W2.x + x3.y * W2.y;
      float t3y = x3.y * W2.x - x3.x * W2.y;
      float B0r = x2.x + t3x, B0i = x2.y + t3y;
      float B1r = x2.x - t3x, B1i = x2.y - t3y;
      // stage s: pairs (A0,B0) w=W1 ; (A1,B1) w=W1b
      float u0x = B0r * W1.x + B0i * W1.y;
      float u0y = B0i * W1.x - B0r * W1.y;
      float u1x = B1r * W1b.x + B1i * W1b.y;
      float u1y = B1i * W1b.x - B1r * W1b.y;
      int p0 = P0[it];
      C[p0]          = make_float2(A0r + u0x, A0i + u0y);
      C[p0 + dq]     = make_float2(A1r + u1x, A1i + u1y);
      C[p0 + 2 * dq] = make_float2(A0r - u0x, A0i - u0y);
      C[p0 + 3 * dq] = make_float2(A1r - u1x, A1i - u1y);
    }
    __syncthreads();
  }

  // ---- fused augmentation epilogue (unchanged) ----
  const float inv512 = 1.0f / 512.0f;
  const u16* lMb = logM + (size_t)b * Nd;
  const u16* lNb = logN + (size_t)b * Nd;
  float* ob = out + (size_t)b * Nd;
  #pragma unroll
  for (int s = 0; s < 8; ++s){
    int qq = (s << 8) + tid;
    int t  = qq >> 2;
    int f4 = qq & 3;
    int f  = f0 + (f4 << 2);
    int j  = f4 << 1;
    int pt = fphys(t);
    int nidx = t * 64 + f;
    float4 xv = *(const float4*)(xb + nidx);
    int wi = warp_idx_(t, wpb, shb);
    float4 wv = *(const float4*)(xb + wi * 64 + f);
    float4 sc = *(const float4*)(scl + b * 64 + f);
    ushort4 mr = *(const ushort4*)(lMb + nidx);
    ushort4 nr4 = *(const ushort4*)(lNb + nidx);
    float2 c0 = C[j * PITCH2 + pt];
    float2 c1 = C[(j + 1) * PITCH2 + pt];
    float fr[4];
    fr[0] = c0.x * inv512;
    fr[1] = c0.y * inv512;
    fr[2] = c1.x * inv512;
    fr[3] = c1.y * inv512;
    const float xvv[4] = {xv.x, xv.y, xv.z, xv.w};
    const float wvv[4] = {wv.x, wv.y, wv.z, wv.w};
    const float scv[4] = {sc.x, sc.y, sc.z, sc.w};
    const u16 mrv[4] = {mr.x, mr.y, mr.z, mr.w};
    const u16 nrv[4] = {nr4.x, nr4.y, nr4.z, nr4.w};
    float o[4];
    #pragma unroll
    for (int c = 0; c < 4; ++c){
      float maskv = sigmoidf_(bf2f(mrv[c]));
      maskv = 1.0f - (1.0f - maskv) * s_mask * 0.3f;
      float nmag = softplusf_(bf2f(nrv[c]));
      float nz = normal_from_bits(rb32(knk.a, knk.b, (u32)(b * Nd + nidx + c)));
      float noise = nz * nmag * s_noise * 0.05f;
      float fq = pass ? xvv[c] : fr[c];
      float aug = fmaf(xvv[c] * maskv, scv[c], noise);
      o[c] = aug * wa + fq * wb + wvv[c] * wc;
    }
    *(float4*)(ob + nidx) = make_float4(o[0], o[1], o[2], o[3]);
  }
}

// ---------------------------------------------------------------------------
extern "C" void kernel_launch(void* const* d_in, const int* in_sizes, int n_in,
                              void* d_out, int out_size, void* d_ws, size_t ws_size,
                              hipStream_t stream)
{
  (void)in_sizes; (void)n_in; (void)out_size; (void)ws_size;
  const float* x   = (const float*)d_in[0];
  const float* w1  = (const float*)d_in[2];
  const float* b1  = (const float*)d_in[3];
  const float* w2  = (const float*)d_in[4];
  const float* b2  = (const float*)d_in[5];
  const float* w3  = (const float*)d_in[6];
  const float* b3  = (const float*)d_in[7];
  const float* wm  = (const float*)d_in[8];
  const float* bm  = (const float*)d_in[9];
  const float* wn  = (const float*)d_in[10];
  const float* bn  = (const float*)d_in[11];
  const float* wsc = (const float*)d_in[12];
  const float* bsc = (const float*)d_in[13];
  const float* pm  = (const float*)d_in[14];
  const float* pn  = (const float*)d_in[15];
  const float* psh = (const float*)d_in[16];
  const float* psc = (const float*)d_in[17];
  float* out = (float*)d_out;
  char* ws = (char*)d_ws;

  int*   wp   = (int*)(ws + 0);
  int*   shv  = (int*)(ws + 1024);
  float* h1   = (float*)(ws + 67584);
  float* h2   = (float*)(ws + 198656);
  u16*   h3b  = (u16*)  (ws + 460800);
  float* scl  = (float*)(ws + 591872);
  u16*   logM = (u16*)  (ws + 1048576);
  u16*   logN = (u16*)  (ws + 1048576 + 16777216);

  k_init <<<dim3(1),       dim3(256), 0, stream>>>(wp, shv, psh);
  k_mlp1 <<<dim3(256),     dim3(128), 0, stream>>>(w1, b1, h1);
  k_mlp2 <<<dim3(256),     dim3(256), 0, stream>>>(h1, w2, b2, h2);
  k_mlp3 <<<dim3(256),     dim3(256), 0, stream>>>(h2, w3, b3, h3b);
  k_scale<<<dim3(64),      dim3(256), 0, stream>>>(h3b, wsc, bsc, psc, scl);
  k_gemm <<<dim3(256, 2),  dim3(256), 0, stream>>>(h3b, wm, bm, wn, bn, logM, logN);
  k_faug <<<dim3(1024),    dim3(256), 0, stream>>>(x, logM, logN, scl, wp, shv,
                                                   pm, pn, psh, out);
}

// Round 2
// 333.447 us; speedup vs baseline: 1.0246x; 1.0246x over previous
//
#include <hip/hip_runtime.h>
#include <cstdint>
#include <cstddef>

// ============================================================================
// MaskGenerator R6: k_faug reverted to the validated R4 FFT (123us); the
// epilogue's per-element noise draw (threefry+erfinv+softplus ~= 60% of
// k_faug's VALU issue) is hoisted into a new k_noise kernel that transforms
// logN IN PLACE (bf16 -> bf16 noise term, same arithmetic, same counters).
// k_faug is VALU-issue bound (R4: 95% VALUBusy), so moving instructions out
// is the lever; LDS-op reduction (R5) was proven a non-lever.
// k_init z-draw stays fused into k_mlp1 (validated R5). k_gemm/MLP unchanged.
// ============================================================================

typedef unsigned int u32;
typedef unsigned short u16;

#define Bd 256
#define Ld 512
#define Fd 64
#define Nd 32768            // Ld*Fd

struct U2 { u32 a, b; };

__device__ __forceinline__ u32 rotl32(u32 x, int r){ return (x << r) | (x >> (32 - r)); }

__device__ __forceinline__ U2 tf2x32(u32 k0, u32 k1, u32 x0, u32 x1){
  u32 ks2 = k0 ^ k1 ^ 0x1BD11BDAu;
  x0 += k0; x1 += k1;
#define TFR4(r0,r1,r2,r3) \
  x0 += x1; x1 = rotl32(x1, r0); x1 ^= x0; \
  x0 += x1; x1 = rotl32(x1, r1); x1 ^= x0; \
  x0 += x1; x1 = rotl32(x1, r2); x1 ^= x0; \
  x0 += x1; x1 = rotl32(x1, r3); x1 ^= x0;
  TFR4(13,15,26,6)  x0 += k1;  x1 += ks2 + 1u;
  TFR4(17,29,16,24) x0 += ks2; x1 += k0 + 2u;
  TFR4(13,15,26,6)  x0 += k0;  x1 += k1 + 3u;
  TFR4(17,29,16,24) x0 += k1;  x1 += ks2 + 4u;
  TFR4(13,15,26,6)  x0 += ks2; x1 += k0 + 5u;
#undef TFR4
  U2 r; r.a = x0; r.b = x1; return r;
}

__device__ __forceinline__ u32 rb32(u32 k0, u32 k1, u32 i){
  U2 r = tf2x32(k0, k1, 0u, i);
  return r.a ^ r.b;
}

__device__ __forceinline__ U2 split_key(u32 k0, u32 k1, u32 j){
  return tf2x32(k0, k1, 0u, j);
}

__device__ __forceinline__ float sigmoidf_(float x){ return 1.0f / (1.0f + expf(-x)); }
__device__ __forceinline__ float softplusf_(float x){ return fmaxf(x, 0.0f) + log1pf(expf(-fabsf(x))); }
__device__ __forceinline__ float leakyf_(float x){ return (x > 0.0f) ? x : 0.2f * x; }

__device__ __forceinline__ float erfinvf_(float x){
  float w = -log1pf(-x * x);
  float p;
  if (w < 5.0f){
    w -= 2.5f;
    p =               2.81022636e-08f;
    p = fmaf(p, w,    3.43273939e-07f);
    p = fmaf(p, w,   -3.5233877e-06f);
    p = fmaf(p, w,   -4.39150654e-06f);
    p = fmaf(p, w,    0.00021858087f);
    p = fmaf(p, w,   -0.00125372503f);
    p = fmaf(p, w,   -0.00417768164f);
    p = fmaf(p, w,    0.246640727f);
    p = fmaf(p, w,    1.50140941f);
  } else {
    w = sqrtf(w) - 3.0f;
    p =              -0.000200214257f;
    p = fmaf(p, w,    0.000100950558f);
    p = fmaf(p, w,    0.00134934322f);
    p = fmaf(p, w,   -0.00367342844f);
    p = fmaf(p, w,    0.00573950773f);
    p = fmaf(p, w,   -0.0076224613f);
    p = fmaf(p, w,    0.00943887047f);
    p = fmaf(p, w,    1.00167406f);
    p = fmaf(p, w,    2.83297682f);
  }
  return p * x;
}

__device__ __forceinline__ float uniform_from_bits(u32 bits){
  return __uint_as_float((bits >> 9) | 0x3f800000u) - 1.0f;
}

__device__ __forceinline__ float normal_from_bits(u32 bits){
  float u01 = uniform_from_bits(bits);
  const float lo = -0.99999994f;
  float v = fmaf(u01, 2.0f, lo);
  v = fmaxf(lo, v);
  return 1.41421356f * erfinvf_(v);
}

__device__ __forceinline__ int warp_idx_(int t, int wp, int sh){
  int tps = t + sh;
  int pos = (t >= wp) ? ((tps < Ld - 1) ? tps : (Ld - 1)) : t;
  int neg = ((t >= wp + sh) && (t < Ld + sh)) ? (t - sh) : t;
  return (sh > 0) ? pos : ((sh < 0) ? neg : t);
}

__device__ __forceinline__ u32 pack_bf16_2(float a, float b){
  u32 ua = __float_as_uint(a), ub = __float_as_uint(b);
  u32 ra = (ua + 0x7FFFu + ((ua >> 16) & 1u)) >> 16;
  u32 rb = (ub + 0x7FFFu + ((ub >> 16) & 1u)) >> 16;
  return (ra & 0xFFFFu) | (rb << 16);
}
__device__ __forceinline__ u16 f2bf(float a){
  u32 ua = __float_as_uint(a);
  return (u16)((ua + 0x7FFFu + ((ua >> 16) & 1u)) >> 16);
}
__device__ __forceinline__ float bf2f(u16 v){
  return __uint_as_float(((u32)v) << 16);
}

__device__ __forceinline__ int swz_(int v){
  return ((v >> 2) & 7) ^ ((v & 3) << 1);
}
__device__ __forceinline__ int rev9_(int k){
  return (int)(__brev((u32)k) >> 23);
}

// ---------------------------------------------------------------------------
// K0: wp/sh randint draws only (z-draw fused into k_mlp1). grid(1) x 256.
// ---------------------------------------------------------------------------
__global__ __launch_bounds__(256) void k_init(int* __restrict__ wp, int* __restrict__ shv,
                                              const float* __restrict__ p_shift){
  int b = threadIdx.x;
  float s_shift = sigmoidf_(p_shift[0]);
  int wsteps = (int)(51.2f * s_shift);
  U2 kwp = split_key(0u, 42u, 2u);
  U2 ksh = split_key(0u, 42u, 3u);
  {
    U2 k1 = split_key(kwp.a, kwp.b, 0u);
    U2 k2 = split_key(kwp.a, kwp.b, 1u);
    u32 hi = rb32(k1.a, k1.b, (u32)b);
    u32 lo = rb32(k2.a, k2.b, (u32)b);
    u32 span = (u32)(Ld - 2 * wsteps);
    u32 mult = 65536u % span; mult = (mult * mult) % span;
    u32 off = ((hi % span) * mult + (lo % span)) % span;
    wp[b] = wsteps + (int)off;
  }
  {
    U2 k1 = split_key(ksh.a, ksh.b, 0u);
    U2 k2 = split_key(ksh.a, ksh.b, 1u);
    u32 hi = rb32(k1.a, k1.b, (u32)b);
    u32 lo = rb32(k2.a, k2.b, (u32)b);
    u32 span = (u32)(2 * wsteps + 1);
    u32 mult = 65536u % span; mult = (mult * mult) % span;
    u32 off = ((hi % span) * mult + (lo % span)) % span;
    shv[b] = -wsteps + (int)off;
  }
}

// ---------------------------------------------------------------------------
// MLP chain. k_mlp1 draws its z-row in LDS (same threefry counters as the
// original k_init: counter = b*64 + k). Validated R5.
// ---------------------------------------------------------------------------
__global__ __launch_bounds__(128) void k_mlp1(const float* __restrict__ w1,
                                              const float* __restrict__ b1, float* __restrict__ h1){
  __shared__ float zs[64];
  int b = blockIdx.x, n = threadIdx.x;
  if (n < 64){
    U2 kz = split_key(0u, 42u, 0u);
    zs[n] = normal_from_bits(rb32(kz.a, kz.b, (u32)(b * 64 + n)));
  }
  __syncthreads();
  float acc = b1[n];
  #pragma unroll 8
  for (int k = 0; k < 64; ++k) acc = fmaf(zs[k], w1[k * 128 + n], acc);
  h1[b * 128 + n] = leakyf_(acc);
}

__global__ __launch_bounds__(256) void k_mlp2(const float* __restrict__ h1, const float* __restrict__ w2,
                                              const float* __restrict__ b2, float* __restrict__ h2){
  int b = blockIdx.x, n = threadIdx.x;
  const float* hr = h1 + b * 128;
  float acc = b2[n];
  #pragma unroll 8
  for (int k = 0; k < 128; ++k) acc = fmaf(hr[k], w2[k * 256 + n], acc);
  h2[b * 256 + n] = leakyf_(acc);
}

__global__ __launch_bounds__(256) void k_mlp3(const float* __restrict__ h2, const float* __restrict__ w3,
                                              const float* __restrict__ b3, u16* __restrict__ h3b){
  int b = blockIdx.x, n = threadIdx.x;
  const float* hr = h2 + b * 256;
  float acc = b3[n];
  #pragma unroll 8
  for (int k = 0; k < 256; ++k) acc = fmaf(hr[k], w3[k * 256 + n], acc);
  h3b[b * 256 + n] = f2bf(leakyf_(acc));
}

__global__ __launch_bounds__(256) void k_scale(const u16* __restrict__ h3b, const float* __restrict__ wsc,
                                               const float* __restrict__ bsc, const float* __restrict__ p_scale,
                                               float* __restrict__ scl){
  int tid = threadIdx.x;
  int b = blockIdx.x * 4 + (tid >> 6);
  int f = tid & 63;
  float acc = bsc[f];
  for (int k = 0; k < 256; ++k) acc = fmaf(bf2f(h3b[b * 256 + k]), wsc[k * 64 + f], acc);
  float s_scale = sigmoidf_(p_scale[0]);
  scl[b * 64 + f] = 1.0f + (softplusf_(acc) - 0.5f) * 0.2f * s_scale;
}

// ---------------------------------------------------------------------------
// k_gemm: unchanged from R3/R4/R5 (validated)
// ---------------------------------------------------------------------------
typedef short short8 __attribute__((ext_vector_type(8)));
typedef float f32x4 __attribute__((ext_vector_type(4)));
union Frag { uint4 u; short8 s; };

__global__ __launch_bounds__(256, 2) void k_gemm(
    const u16* __restrict__ h3b,
    const float* __restrict__ wm, const float* __restrict__ bm,
    const float* __restrict__ wn, const float* __restrict__ bn,
    u16* __restrict__ logM, u16* __restrict__ logN)
{
  __shared__ __align__(16) u32 As [128 * 32];
  __shared__ __align__(16) u32 Bs0[128 * 32];
  __shared__ __align__(16) u32 Bs1[128 * 32];

  const int tid  = threadIdx.x;
  const int lane = tid & 63;
  const int w    = tid >> 6;
  const int q    = lane >> 4;
  const int lo   = lane & 15;
  const int nt0  = blockIdx.x << 7;
  const int b0   = blockIdx.y << 7;
  const int wr   = (w >> 1) << 6;
  const int wc   = (w & 1) << 6;

  const int p  = lane >> 3;
  const int c8 = lane & 7;
  const int nb = (w << 5) + (p << 2);

  f32x4 accm[4][4], accn[4][4];
  #pragma unroll
  for (int i = 0; i < 4; ++i)
    #pragma unroll
    for (int j = 0; j < 4; ++j){ accm[i][j] = (f32x4)0.0f; accn[i][j] = (f32x4)0.0f; }

  for (int kc = 0; kc < 256; kc += 64){
    if (kc) __syncthreads();
    #pragma unroll
    for (int j = 0; j < 4; ++j){
      int idx  = j * 256 + tid;
      int row  = idx >> 3;
      int slot = idx & 7;
      int g    = slot ^ swz_(row);
      uint4 v  = *(const uint4*)(h3b + (size_t)(b0 + row) * 256 + kc + g * 8);
      *(uint4*)&As[row * 32 + slot * 4] = v;
    }
    #pragma unroll
    for (int cp = 0; cp < 4; ++cp){
      int c = cp * 8 + c8;
      size_t gb = (size_t)(kc + 2 * c) * Nd + nt0 + nb;
      float4 m0 = *(const float4*)(wm + gb);
      float4 m1 = *(const float4*)(wm + gb + Nd);
      float4 v0 = *(const float4*)(wn + gb);
      float4 v1 = *(const float4*)(wn + gb + Nd);
      int g = c >> 2, cl = c & 3;
      #pragma unroll
      for (int s = 0; s < 4; ++s){
        int n = nb + s;
        int addr = n * 32 + (g ^ swz_(n)) * 4 + cl;
        float a0 = (s == 0) ? m0.x : (s == 1) ? m0.y : (s == 2) ? m0.z : m0.w;
        float a1 = (s == 0) ? m1.x : (s == 1) ? m1.y : (s == 2) ? m1.z : m1.w;
        float b0f = (s == 0) ? v0.x : (s == 1) ? v0.y : (s == 2) ? v0.z : v0.w;
        float b1f = (s == 0) ? v1.x : (s == 1) ? v1.y : (s == 2) ? v1.z : v1.w;
        Bs0[addr] = pack_bf16_2(a0, a1);
        Bs1[addr] = pack_bf16_2(b0f, b1f);
      }
    }
    __syncthreads();

    #pragma unroll
    for (int u = 0; u < 2; ++u){
      int G = u * 4 + q;
      Frag af[4], bfm[4], bfn[4];
      #pragma unroll
      for (int mt = 0; mt < 4; ++mt){
        int row = wr + mt * 16 + lo;
        af[mt].u = *(const uint4*)&As[row * 32 + (G ^ swz_(row)) * 4];
      }
      #pragma unroll
      for (int nt = 0; nt < 4; ++nt){
        int n = wc + nt * 16 + lo;
        int ad = n * 32 + (G ^ swz_(n)) * 4;
        bfm[nt].u = *(const uint4*)&Bs0[ad];
        bfn[nt].u = *(const uint4*)&Bs1[ad];
      }
      #pragma unroll
      for (int mt = 0; mt < 4; ++mt){
        #pragma unroll
        for (int nt = 0; nt < 4; ++nt){
          accm[mt][nt] = __builtin_amdgcn_mfma_f32_16x16x32_bf16(af[mt].s, bfm[nt].s, accm[mt][nt], 0, 0, 0);
          accn[mt][nt] = __builtin_amdgcn_mfma_f32_16x16x32_bf16(af[mt].s, bfn[nt].s, accn[mt][nt], 0, 0, 0);
        }
      }
    }
  }

  #pragma unroll
  for (int nt = 0; nt < 4; ++nt){
    int n = nt0 + wc + nt * 16 + lo;
    float bmv = bm[n];
    float bnv = bn[n];
    #pragma unroll
    for (int mt = 0; mt < 4; ++mt){
      #pragma unroll
      for (int r = 0; r < 4; ++r){
        int b = b0 + wr + mt * 16 + q * 4 + r;
        size_t o = (size_t)b * Nd + n;
        logM[o] = f2bf(accm[mt][nt][r] + bmv);
        logN[o] = f2bf(accn[mt][nt][r] + bnv);
      }
    }
  }
}

// ---------------------------------------------------------------------------
// k_noise: in-place transform of logN (bf16 noise-magnitude logits) into the
// final per-element noise term: noise = N(0,1)[ctr] * softplus(logit)
// * s_noise * 0.05, stored bf16. Arithmetic and threefry counters are
// identical to the validated R4 k_faug epilogue path (counter = flat element
// index b*Nd + n); the only delta is one bf16 rounding of the noise term
// (|noise| <~ 0.3 -> added error <~ 6e-4, well under tolerance).
// 4096 blocks x 256 threads x 8 elements. Pure VALU, >16 waves/CU.
// ---------------------------------------------------------------------------
__global__ __launch_bounds__(256) void k_noise(u16* __restrict__ logN,
                                               const float* __restrict__ p_noise){
  int gid = blockIdx.x * 256 + threadIdx.x;
  u32 base = (u32)gid * 8u;
  float s_noise = sigmoidf_(p_noise[0]);
  float sc = s_noise * 0.05f;
  U2 knk = split_key(0u, 42u, 1u);

  uint4 v = *(const uint4*)(logN + base);
  u32 wds[4] = {v.x, v.y, v.z, v.w};
  u32 outw[4];
  #pragma unroll
  for (int h = 0; h < 4; ++h){
    u16 l0 = (u16)(wds[h] & 0xFFFFu);
    u16 l1 = (u16)(wds[h] >> 16);
    float nm0 = softplusf_(bf2f(l0));
    float nm1 = softplusf_(bf2f(l1));
    float nz0 = normal_from_bits(rb32(knk.a, knk.b, base + (u32)(2 * h)));
    float nz1 = normal_from_bits(rb32(knk.a, knk.b, base + (u32)(2 * h + 1)));
    outw[h] = pack_bf16_2(nz0 * nm0 * sc, nz1 * nm1 * sc);
  }
  *(uint4*)(logN + base) = make_uint4(outw[0], outw[1], outw[2], outw[3]);
}

// ---------------------------------------------------------------------------
// k_faug: validated R4 structure (SoA SR/SI, pitch 529, lphys t+(t>>5),
// per-stage radix-2 FFT, masked Hermitian repack, inverse, fused epilogue).
// Only change vs R4: the noise term is READ from noiseT (pre-computed by
// k_noise) instead of computing threefry+erfinv+softplus per element here.
// ---------------------------------------------------------------------------
#define PITCH 529

__device__ __forceinline__ int lphys(int t){ return t + (t >> 5); }

__global__ __launch_bounds__(256, 4) void k_faug(
    const float* __restrict__ x,
    const u16* __restrict__ logM, const u16* __restrict__ noiseT,
    const float* __restrict__ scl,
    const int* __restrict__ wp, const int* __restrict__ shv,
    const float* __restrict__ p_mask, const float* __restrict__ p_noise,
    const float* __restrict__ p_shift,
    float* __restrict__ out)
{
  __shared__ float SR[8 * PITCH];
  __shared__ float SI[8 * PITCH];
  __shared__ float2 tw[256];

  const int tid = threadIdx.x;
  const int b   = blockIdx.x >> 2;
  const int f0  = (blockIdx.x & 3) << 4;

  float s_mask  = sigmoidf_(p_mask[0]);
  float s_shift = sigmoidf_(p_shift[0]);
  float s_mix   = 1.0f - s_shift;
  float ratio   = fminf(s_mix * 0.1f, 0.5f);
  float wa = 1.0f - s_mix - s_shift;
  wa = fminf(fmaxf(wa, 0.1f), 0.8f);
  float wb = s_mix * 0.5f;
  float wc = s_shift * 0.5f;
  float tot = wa + wb + wc;
  wa /= tot; wb /= tot; wc /= tot;
  bool pass = (s_mix < 0.01f);
  (void)p_noise;

  U2 kf  = split_key(0u, 42u, 4u);
  const int wpb = wp[b];
  const int shb = shv[b];

  {
    float ang = -6.283185307179586f * ((float)tid / 512.0f);
    tw[tid] = make_float2(cosf(ang), sinf(ang));
  }

  // ---- stage in + pack pairs ----
  const float* xb = x + (size_t)b * Nd;
  #pragma unroll
  for (int s = 0; s < 8; ++s){
    int qq = (s << 8) + tid;        // float4 id, 0..2047
    int t  = qq >> 2;
    int f4 = qq & 3;
    float4 v = *(const float4*)(xb + t * 64 + f0 + (f4 << 2));
    int j = f4 << 1;
    int pt = lphys(t);
    SR[j * PITCH + pt]       = v.x;  SI[j * PITCH + pt]       = v.y;
    SR[(j + 1) * PITCH + pt] = v.z;  SI[(j + 1) * PITCH + pt] = v.w;
  }
  __syncthreads();

  // ---- forward DIF (natural in -> bitrev out) ----
  for (int s = 9; s >= 1; --s){
    int half = 1 << (s - 1);
    #pragma unroll
    for (int it = 0; it < 8; ++it){
      int j  = it;                  // one series per sweep; lanes span bfly idx
      int bi = tid;
      int pos = bi & (half - 1);
      int g = bi >> (s - 1);
      int i1 = (g << s) + pos;
      int i2 = i1 + half;
      int a1 = j * PITCH + lphys(i1);
      int a2 = j * PITCH + lphys(i2);
      float ur = SR[a1], ui = SI[a1];
      float vr = SR[a2], vi = SI[a2];
      SR[a1] = ur + vr; SI[a1] = ui + vi;
      float dr = ur - vr, di = ui - vi;
      float2 w = tw[pos << (9 - s)];
      SR[a2] = dr * w.x - di * w.y;
      SI[a2] = dr * w.y + di * w.x;
    }
    __syncthreads();
  }

  // ---- masked Hermitian repack at natural frequency k ----
  // slot k in [0,255]; k=0 also handles k=256 (both self-paired).
  #pragma unroll
  for (int it = 0; it < 8; ++it){
    int j = it;
    int k = tid;
    int nItr = (k == 0) ? 2 : 1;
    for (int e = 0; e < nItr; ++e){
      int kk = (e == 0) ? k : 256;
      int nk = (512 - kk) & 511;
      int pk = rev9_(kk), pn = rev9_(nk);
      int ak = j * PITCH + lphys(pk);
      int an = j * PITCH + lphys(pn);
      float zkr = SR[ak], zki = SI[ak];
      float znr = SR[an], zni = SI[an];
      float X0r = 0.5f * (zkr + znr), X0i = 0.5f * (zki - zni);
      float X1r = 0.5f * (zki + zni), X1i = 0.5f * (znr - zkr);
      int fA = f0 + (j << 1);
      u32 ck = (u32)((b * Ld + kk) * Fd + fA);
      u32 cn = (u32)((b * Ld + nk) * Fd + fA);
      float k0a = (uniform_from_bits(rb32(kf.a, kf.b, ck))      > ratio) ? 1.0f : 0.0f;
      float k0b = (uniform_from_bits(rb32(kf.a, kf.b, cn))      > ratio) ? 1.0f : 0.0f;
      float k1a = (uniform_from_bits(rb32(kf.a, kf.b, ck + 1u)) > ratio) ? 1.0f : 0.0f;
      float k1b = (uniform_from_bits(rb32(kf.a, kf.b, cn + 1u)) > ratio) ? 1.0f : 0.0f;
      float m0 = 0.5f * (k0a + k0b);
      float m1 = 0.5f * (k1a + k1b);
      // U[k] = m0*X0 + i*m1*X1 ; U[nk] = m0*conj(X0) + i*m1*conj(X1)
      SR[ak] = m0 * X0r - m1 * X1i;
      SI[ak] = m0 * X0i + m1 * X1r;
      SR[an] = m0 * X0r + m1 * X1i;
      SI[an] = m1 * X1r - m0 * X0i;
    }
  }
  __syncthreads();

  // ---- inverse DIT (bitrev in -> natural out) ----
  for (int s = 1; s <= 9; ++s){
    int half = 1 << (s - 1);
    #pragma unroll
    for (int it = 0; it < 8; ++it){
      int j  = it;
      int bi = tid;
      int pos = bi & (half - 1);
      int g = bi >> (s - 1);
      int i1 = (g << s) + pos;
      int i2 = i1 + half;
      int a1 = j * PITCH + lphys(i1);
      int a2 = j * PITCH + lphys(i2);
      float2 w = tw[pos << (9 - s)];
      float vr = SR[a2], vi = SI[a2];
      float tx_ = vr * w.x + vi * w.y;    // v * conj(w)
      float ty_ = vi * w.x - vr * w.y;
      float ur = SR[a1], ui = SI[a1];
      SR[a1] = ur + tx_; SI[a1] = ui + ty_;
      SR[a2] = ur - tx_; SI[a2] = ui - ty_;
    }
    __syncthreads();
  }

  // ---- fused augmentation epilogue ----
  const float inv512 = 1.0f / 512.0f;
  const u16* lMb = logM + (size_t)b * Nd;
  const u16* lNb = noiseT + (size_t)b * Nd;
  float* ob = out + (size_t)b * Nd;
  #pragma unroll
  for (int s = 0; s < 8; ++s){
    int qq = (s << 8) + tid;
    int t  = qq >> 2;
    int f4 = qq & 3;
    int f  = f0 + (f4 << 2);
    int j  = f4 << 1;
    int pt = lphys(t);
    int nidx = t * 64 + f;
    float4 xv = *(const float4*)(xb + nidx);
    int wi = warp_idx_(t, wpb, shb);
    float4 wv = *(const float4*)(xb + wi * 64 + f);
    float4 sc = *(const float4*)(scl + b * 64 + f);
    ushort4 mr = *(const ushort4*)(lMb + nidx);
    ushort4 nr4 = *(const ushort4*)(lNb + nidx);
    float fr[4];
    fr[0] = SR[j * PITCH + pt] * inv512;
    fr[1] = SI[j * PITCH + pt] * inv512;
    fr[2] = SR[(j + 1) * PITCH + pt] * inv512;
    fr[3] = SI[(j + 1) * PITCH + pt] * inv512;
    const float xvv[4] = {xv.x, xv.y, xv.z, xv.w};
    const float wvv[4] = {wv.x, wv.y, wv.z, wv.w};
    const float scv[4] = {sc.x, sc.y, sc.z, sc.w};
    const u16 mrv[4] = {mr.x, mr.y, mr.z, mr.w};
    const u16 nrv[4] = {nr4.x, nr4.y, nr4.z, nr4.w};
    float o[4];
    #pragma unroll
    for (int c = 0; c < 4; ++c){
      float maskv = sigmoidf_(bf2f(mrv[c]));
      maskv = 1.0f - (1.0f - maskv) * s_mask * 0.3f;
      float noise = bf2f(nrv[c]);
      float fq = pass ? xvv[c] : fr[c];
      float aug = fmaf(xvv[c] * maskv, scv[c], noise);
      o[c] = aug * wa + fq * wb + wvv[c] * wc;
    }
    *(float4*)(ob + nidx) = make_float4(o[0], o[1], o[2], o[3]);
  }
}

// ---------------------------------------------------------------------------
extern "C" void kernel_launch(void* const* d_in, const int* in_sizes, int n_in,
                              void* d_out, int out_size, void* d_ws, size_t ws_size,
                              hipStream_t stream)
{
  (void)in_sizes; (void)n_in; (void)out_size; (void)ws_size;
  const float* x   = (const float*)d_in[0];
  const float* w1  = (const float*)d_in[2];
  const float* b1  = (const float*)d_in[3];
  const float* w2  = (const float*)d_in[4];
  const float* b2  = (const float*)d_in[5];
  const float* w3  = (const float*)d_in[6];
  const float* b3  = (const float*)d_in[7];
  const float* wm  = (const float*)d_in[8];
  const float* bm  = (const float*)d_in[9];
  const float* wn  = (const float*)d_in[10];
  const float* bn  = (const float*)d_in[11];
  const float* wsc = (const float*)d_in[12];
  const float* bsc = (const float*)d_in[13];
  const float* pm  = (const float*)d_in[14];
  const float* pn  = (const float*)d_in[15];
  const float* psh = (const float*)d_in[16];
  const float* psc = (const float*)d_in[17];
  float* out = (float*)d_out;
  char* ws = (char*)d_ws;

  int*   wp   = (int*)(ws + 0);
  int*   shv  = (int*)(ws + 1024);
  float* h1   = (float*)(ws + 67584);
  float* h2   = (float*)(ws + 198656);
  u16*   h3b  = (u16*)  (ws + 460800);
  float* scl  = (float*)(ws + 591872);
  u16*   logM = (u16*)  (ws + 1048576);
  u16*   logN = (u16*)  (ws + 1048576 + 16777216);

  k_init <<<dim3(1),       dim3(256), 0, stream>>>(wp, shv, psh);
  k_mlp1 <<<dim3(256),     dim3(128), 0, stream>>>(w1, b1, h1);
  k_mlp2 <<<dim3(256),     dim3(256), 0, stream>>>(h1, w2, b2, h2);
  k_mlp3 <<<dim3(256),     dim3(256), 0, stream>>>(h2, w3, b3, h3b);
  k_scale<<<dim3(64),      dim3(256), 0, stream>>>(h3b, wsc, bsc, psc, scl);
  k_gemm <<<dim3(256, 2),  dim3(256), 0, stream>>>(h3b, wm, bm, wn, bn, logM, logN);
  k_noise<<<dim3(4096),    dim3(256), 0, stream>>>(logN, pn);
  k_faug <<<dim3(1024),    dim3(256), 0, stream>>>(x, logM, logN, scl, wp, shv,
                                                   pm, pn, psh, out);
}